// Round 4
// baseline (305.840 us; speedup 1.0000x reference)
//
#include <hip/hip_runtime.h>
#include <hip/hip_bf16.h>

typedef __hip_bfloat16 bf16_t;
typedef __bf16 bf16x8 __attribute__((ext_vector_type(8)));      // 16x16x32 A/B frag
typedef __bf16 bf16x4 __attribute__((ext_vector_type(4)));      // 16x16x16 A/B frag
typedef short  s16x4  __attribute__((ext_vector_type(4)));
typedef float  f32x4  __attribute__((ext_vector_type(4)));      // C/D frag

#define MFMA(a, b, c) __builtin_amdgcn_mfma_f32_16x16x32_bf16((a), (b), (c), 0, 0, 0)

__device__ __forceinline__ f32x4 mfma16(bf16x4 a, bf16x4 b, f32x4 c) {
#if __has_builtin(__builtin_amdgcn_mfma_f32_16x16x16_bf16)
  return __builtin_amdgcn_mfma_f32_16x16x16_bf16(a, b, c, 0, 0, 0);
#else
  return __builtin_amdgcn_mfma_f32_16x16x16bf16_1k(
      __builtin_bit_cast(s16x4, a), __builtin_bit_cast(s16x4, b), c, 0, 0, 0);
#endif
}

__device__ __forceinline__ bf16x8 ldg8(const bf16_t* p) {
  return *reinterpret_cast<const bf16x8*>(p);
}
__device__ __forceinline__ bf16x4 ldg4(const bf16_t* p) {
  return *reinterpret_cast<const bf16x4*>(p);
}
__device__ __forceinline__ void st8(bf16_t* p, bf16x8 v) {
  *reinterpret_cast<bf16x8*>(p) = v;
}
__device__ __forceinline__ void store_out(bf16_t* p, float v) { *p = __float2bfloat16(v); }
__device__ __forceinline__ void store_out(float* p, float v)  { *p = v; }

// async global->LDS, 16B per lane. LDS dest is wave-uniform base + lane*16.
__device__ __forceinline__ void async16(const bf16_t* g, bf16_t* l) {
  __builtin_amdgcn_global_load_lds(
      (const __attribute__((address_space(1))) void*)g,
      (__attribute__((address_space(3))) void*)l, 16, 0, 0);
}

// ---------------------------------------------------------------------------
// f32 -> bf16 conversion; folds softmax scale (1/8 * log2e) into Wq.
// ---------------------------------------------------------------------------
__global__ __launch_bounds__(256) void cvt_kernel(
    const float* __restrict__ x,  const float* __restrict__ Wq,
    const float* __restrict__ Wk, const float* __restrict__ Wv,
    const float* __restrict__ Wo,
    bf16_t* __restrict__ xb,  bf16_t* __restrict__ Wqb,
    bf16_t* __restrict__ Wkb, bf16_t* __restrict__ Wvb,
    bf16_t* __restrict__ Wob) {
  const int bid = blockIdx.x;
  const float* src; bf16_t* dst; size_t base;
  float scl = 1.0f;
  if (bid < 2048)      { src = x;  dst = xb;  base = (size_t)bid * 2048; }
  else if (bid < 2560) { src = Wq; dst = Wqb; base = (size_t)(bid - 2048) * 2048;
                         scl = 0.180336878f; }  // 0.125 * log2(e)
  else if (bid < 3072) { src = Wk; dst = Wkb; base = (size_t)(bid - 2560) * 2048; }
  else if (bid < 3584) { src = Wv; dst = Wvb; base = (size_t)(bid - 3072) * 2048; }
  else                 { src = Wo; dst = Wob; base = (size_t)(bid - 3584) * 2048; }
  const size_t i0 = base + (size_t)threadIdx.x * 8;
  const float4 f0 = *reinterpret_cast<const float4*>(src + i0);
  const float4 f1 = *reinterpret_cast<const float4*>(src + i0 + 4);
  bf16x8 v;
  v[0] = (__bf16)(f0.x * scl); v[1] = (__bf16)(f0.y * scl);
  v[2] = (__bf16)(f0.z * scl); v[3] = (__bf16)(f0.w * scl);
  v[4] = (__bf16)(f1.x * scl); v[5] = (__bf16)(f1.y * scl);
  v[6] = (__bf16)(f1.z * scl); v[7] = (__bf16)(f1.w * scl);
  st8(dst + i0, v);
}

// ---------------------------------------------------------------------------
// GEMM tile: C[128x128] = A[128xK] * B[128xK]^T, K=1024, BK=64 (16 iters,
// half the barriers of BK=32). global_load_lds width-16 staging with
// XOR-chunk swizzle (slot s at row r holds chunk s^(r&7)) -> frag b128
// reads are 2-way (free) instead of 8/16-way.
// ---------------------------------------------------------------------------
#define GK 1024

template <typename OutT, bool BIAS>
__device__ __forceinline__ void gemm_tile(
    const bf16_t* __restrict__ A, const bf16_t* __restrict__ B,
    OutT* __restrict__ C, const float* __restrict__ bias,
    int bm, int bn, int ldc, bf16_t* As, bf16_t* Bs) {
  const int tid  = threadIdx.x;
  const int lane = tid & 63;
  const int wave = tid >> 6;
  const int wm   = (wave & 1) << 6;
  const int wn   = (wave >> 1) << 6;
  const int lr   = lane & 15;
  const int lq   = lane >> 4;

  const int srow = tid >> 3;                        // 0..31
  const int sx   = ((tid & 7) ^ (srow & 7)) << 3;   // swizzled source offset

  const bf16_t* Ag = A + (size_t)(bm + srow) * GK + sx;
  const bf16_t* Bg = B + (size_t)(bn + srow) * GK + sx;
  bf16_t* Asw = As + wave * 512;
  bf16_t* Bsw = Bs + wave * 512;

  f32x4 acc[4][4];
#pragma unroll
  for (int i = 0; i < 4; ++i)
#pragma unroll
    for (int j = 0; j < 4; ++j) acc[i][j] = (f32x4){0.f, 0.f, 0.f, 0.f};

  for (int k0 = 0; k0 < GK; k0 += 64) {
    __syncthreads();
#pragma unroll
    for (int g = 0; g < 4; ++g) {
      async16(Ag + k0 + (size_t)(g * 32) * GK, Asw + g * 2048);
      async16(Bg + k0 + (size_t)(g * 32) * GK, Bsw + g * 2048);
    }
    __syncthreads();
#pragma unroll
    for (int ks = 0; ks < 2; ++ks) {
      bf16x8 af[4], bf[4];
      const int chs = ((ks * 4 + lq) ^ (lr & 7)) << 3;
#pragma unroll
      for (int i = 0; i < 4; ++i) {
        af[i] = ldg8(&As[(wm + i * 16 + lr) * 64 + chs]);
        bf[i] = ldg8(&Bs[(wn + i * 16 + lr) * 64 + chs]);
      }
#pragma unroll
      for (int mi = 0; mi < 4; ++mi)
#pragma unroll
        for (int ni = 0; ni < 4; ++ni)
          acc[mi][ni] = MFMA(af[mi], bf[ni], acc[mi][ni]);
    }
  }

  // C/D layout: col = lane&15, row = (lane>>4)*4 + r  (m89-verified)
#pragma unroll
  for (int ni = 0; ni < 4; ++ni) {
    const int col = bn + wn + ni * 16 + lr;
    float bv = 0.f;
    if (BIAS) bv = bias[col];
#pragma unroll
    for (int mi = 0; mi < 4; ++mi) {
#pragma unroll
      for (int r = 0; r < 4; ++r) {
        const int row = bm + wm + mi * 16 + lq * 4 + r;
        store_out(&C[(size_t)row * ldc + col], acc[mi][ni][r] + bv);
      }
    }
  }
}

// z=0: Q = x Wq^T [4096x1024];  z=1: K = x Wk^T;  z=2: Vt = Wv x^T [1024x4096]
__global__ __launch_bounds__(256) void qkv_kernel(
    const bf16_t* __restrict__ x, const bf16_t* __restrict__ Wq,
    const bf16_t* __restrict__ Wk, const bf16_t* __restrict__ Wv,
    bf16_t* __restrict__ Q, bf16_t* __restrict__ Kp, bf16_t* __restrict__ Vt) {
  __shared__ alignas(16) bf16_t As[128 * 64];
  __shared__ alignas(16) bf16_t Bs[128 * 64];
  const int bid = blockIdx.x;
  const int z   = blockIdx.y;
  if (z == 0) {
    gemm_tile<bf16_t, false>(x, Wq, Q, nullptr, (bid >> 3) * 128, (bid & 7) * 128, 1024, As, Bs);
  } else if (z == 1) {
    gemm_tile<bf16_t, false>(x, Wk, Kp, nullptr, (bid >> 3) * 128, (bid & 7) * 128, 1024, As, Bs);
  } else {
    gemm_tile<bf16_t, false>(Wv, x, Vt, nullptr, (bid & 7) * 128, (bid >> 3) * 128, 4096, As, Bs);
  }
}

__global__ __launch_bounds__(256) void out_proj_kernel(
    const bf16_t* __restrict__ Ao, const bf16_t* __restrict__ Wo,
    const float* __restrict__ bias, float* __restrict__ out) {
  __shared__ alignas(16) bf16_t As[128 * 64];
  __shared__ alignas(16) bf16_t Bs[128 * 64];
  const int bid = blockIdx.x;
  gemm_tile<float, true>(Ao, Wo, out, bias, (bid >> 3) * 128, (bid & 7) * 128, 1024, As, Bs);
}

// ---------------------------------------------------------------------------
// Attention, S^T formulation, no LDS / no barriers in the hot loop.
// grid (32 qtiles, 32 b*h), 4 waves. Each wave: ALL 64 Q-rows (regs) x its
// own 512-kv stripe in 32 steps of 16 kv. S^T = K·Q^T via 16x16x32 MFMA; its
// C-layout (col=q, row kv=quad*4+r) IS the 16x16x16 B-layout, so P = exp2(S^T)
// feeds PV (O^T = Vt·P) straight from registers. K/V frags load direct from
// global (L2-resident), 1-step software pipeline. Cross-wave O/l reduction
// via ds_add_f32 once at the end.
// ---------------------------------------------------------------------------
#define OLD 65

__global__ __launch_bounds__(256) void attn_kernel(
    const bf16_t* __restrict__ Q, const bf16_t* __restrict__ Kp,
    const bf16_t* __restrict__ Vt, bf16_t* __restrict__ Ao) {
  __shared__ float Olds[64 * OLD];
  __shared__ float Llds[64];

  const int tid  = threadIdx.x;
  const int lane = tid & 63;
  const int wave = tid >> 6;
  const int lr   = lane & 15;
  const int lq   = lane >> 4;
  const int qt   = blockIdx.x;
  const int bh   = blockIdx.y;
  const int b    = bh >> 4;
  const int h    = bh & 15;
  const size_t tok0 = (size_t)b * 2048;
  const int col0 = h * 64;

  for (int i = tid; i < 64 * OLD; i += 256) Olds[i] = 0.f;
  if (tid < 64) Llds[tid] = 0.f;
  __syncthreads();

  // Q B-frags (n=lane&15 -> q-row, k=hd): 4 n-tiles x 2 hd-chunks
  bf16x8 qf[4][2];
  const size_t qbase = (tok0 + qt * 64) * 1024 + col0;
#pragma unroll
  for (int nt = 0; nt < 4; ++nt)
#pragma unroll
    for (int c = 0; c < 2; ++c)
      qf[nt][c] = ldg8(&Q[qbase + (size_t)(nt * 16 + lr) * 1024 + c * 32 + lq * 8]);

  f32x4 o[4][4];  // [ht][nt] : O^T[hd][q]
#pragma unroll
  for (int i = 0; i < 4; ++i)
#pragma unroll
    for (int j = 0; j < 4; ++j) o[i][j] = (f32x4){0.f, 0.f, 0.f, 0.f};
  f32x4 lsum = {0.f, 0.f, 0.f, 0.f};

  const size_t kvbase = tok0 + wave * 512;
  // K A-frag base: m=lane&15 -> kv row, k = c*32 + lq*8
  const bf16_t* Kb = Kp + (kvbase + lr) * 1024 + col0 + lq * 8;
  // V A-frag base: m=lane&15 -> hd row (per ht), k = kv = lq*4 + i
  const bf16_t* Vb = Vt + (size_t)(col0 + lr) * 4096 + kvbase + lq * 4;

  bf16x8 kf[2][2];
  bf16x4 vf[2][4];
  // prologue: step 0
#pragma unroll
  for (int c = 0; c < 2; ++c) kf[0][c] = ldg8(Kb + c * 32);
#pragma unroll
  for (int ht = 0; ht < 4; ++ht) vf[0][ht] = ldg4(Vb + (size_t)(ht * 16) * 4096);

#pragma unroll 2
  for (int s = 0; s < 32; ++s) {
    const int cur = s & 1;
    if (s < 31) {
      const int nxt = cur ^ 1;
      const size_t ko = (size_t)(s + 1) * 16 * 1024;
      const size_t vo = (size_t)(s + 1) * 16;
#pragma unroll
      for (int c = 0; c < 2; ++c) kf[nxt][c] = ldg8(Kb + ko + c * 32);
#pragma unroll
      for (int ht = 0; ht < 4; ++ht) vf[nxt][ht] = ldg4(Vb + (size_t)(ht * 16) * 4096 + vo);
    }
#pragma unroll
    for (int nt = 0; nt < 4; ++nt) {
      f32x4 sN = {0.f, 0.f, 0.f, 0.f};
      sN = MFMA(kf[cur][0], qf[nt][0], sN);
      sN = MFMA(kf[cur][1], qf[nt][1], sN);
      const float p0 = exp2f(sN.x);
      const float p1 = exp2f(sN.y);
      const float p2 = exp2f(sN.z);
      const float p3 = exp2f(sN.w);
      bf16x4 pb;
      pb[0] = (__bf16)p0; pb[1] = (__bf16)p1;
      pb[2] = (__bf16)p2; pb[3] = (__bf16)p3;
      lsum[nt] += (p0 + p1) + (p2 + p3);
#pragma unroll
      for (int ht = 0; ht < 4; ++ht)
        o[ht][nt] = mfma16(vf[cur][ht], pb, o[ht][nt]);
    }
  }

  // reduce O^T and l across the 4 waves (different kv stripes)
#pragma unroll
  for (int ht = 0; ht < 4; ++ht)
#pragma unroll
    for (int nt = 0; nt < 4; ++nt)
#pragma unroll
      for (int r = 0; r < 4; ++r)
        atomicAdd(&Olds[(ht * 16 + lq * 4 + r) * OLD + nt * 16 + lr], o[ht][nt][r]);
#pragma unroll
  for (int nt = 0; nt < 4; ++nt) atomicAdd(&Llds[nt * 16 + lr], lsum[nt]);
  __syncthreads();

  // epilogue: thread t -> q = t>>2, hd segment = (t&3)*16; coalesced 32B store
  const int q  = tid >> 2;
  const int hs = (tid & 3) * 16;
  const float invl = 1.f / Llds[q];
  bf16x8 w0, w1;
#pragma unroll
  for (int i = 0; i < 8; ++i) {
    w0[i] = (__bf16)(Olds[(hs + i) * OLD + q] * invl);
    w1[i] = (__bf16)(Olds[(hs + 8 + i) * OLD + q] * invl);
  }
  bf16_t* dst = Ao + (tok0 + qt * 64 + q) * 1024 + col0 + hs;
  st8(dst, w0);
  st8(dst + 8, w1);
}

extern "C" void kernel_launch(void* const* d_in, const int* in_sizes, int n_in,
                              void* d_out, int out_size, void* d_ws, size_t ws_size,
                              hipStream_t stream) {
  const float* x  = (const float*)d_in[0];
  const float* Wq = (const float*)d_in[1];
  const float* Wk = (const float*)d_in[2];
  const float* Wv = (const float*)d_in[3];
  const float* Wo = (const float*)d_in[4];
  const float* bo = (const float*)d_in[5];
  float* out = (float*)d_out;

  const size_t NTOK = 4096, DMODEL = 1024, WSZ = DMODEL * DMODEL;
  bf16_t* xb  = (bf16_t*)d_ws;
  bf16_t* Wqb = xb + NTOK * DMODEL;
  bf16_t* Wkb = Wqb + WSZ;
  bf16_t* Wvb = Wkb + WSZ;
  bf16_t* Wob = Wvb + WSZ;
  bf16_t* Q   = Wob + WSZ;
  bf16_t* Kp  = Q  + NTOK * DMODEL;
  bf16_t* Vt  = Kp + NTOK * DMODEL;            // [1024][4096] = V^T
  bf16_t* Ao  = Vt + NTOK * DMODEL;

  cvt_kernel<<<dim3(4096), 256, 0, stream>>>(x, Wq, Wk, Wv, Wo, xb, Wqb, Wkb, Wvb, Wob);
  qkv_kernel<<<dim3(256, 3), 256, 0, stream>>>(xb, Wqb, Wkb, Wvb, Q, Kp, Vt);
  attn_kernel<<<dim3(32, 32), 256, 0, stream>>>(Q, Kp, Vt, Ao);
  out_proj_kernel<<<dim3(256, 1), 256, 0, stream>>>(Ao, Wob, bo, out);
}

// Round 5
// 217.871 us; speedup vs baseline: 1.4038x; 1.4038x over previous
//
#include <hip/hip_runtime.h>
#include <hip/hip_bf16.h>

typedef __hip_bfloat16 bf16_t;
typedef __bf16 bf16x8 __attribute__((ext_vector_type(8)));      // 16x16x32 A/B frag
typedef __bf16 bf16x4 __attribute__((ext_vector_type(4)));      // 16x16x16 A/B frag
typedef short  s16x4  __attribute__((ext_vector_type(4)));
typedef float  f32x4  __attribute__((ext_vector_type(4)));      // C/D frag

#define MFMA(a, b, c) __builtin_amdgcn_mfma_f32_16x16x32_bf16((a), (b), (c), 0, 0, 0)

__device__ __forceinline__ f32x4 mfma16(bf16x4 a, bf16x4 b, f32x4 c) {
#if __has_builtin(__builtin_amdgcn_mfma_f32_16x16x16_bf16)
  return __builtin_amdgcn_mfma_f32_16x16x16_bf16(a, b, c, 0, 0, 0);
#else
  return __builtin_amdgcn_mfma_f32_16x16x16bf16_1k(
      __builtin_bit_cast(s16x4, a), __builtin_bit_cast(s16x4, b), c, 0, 0, 0);
#endif
}

__device__ __forceinline__ bf16x8 ldg8(const bf16_t* p) {
  return *reinterpret_cast<const bf16x8*>(p);
}
__device__ __forceinline__ bf16x4 ldg4(const bf16_t* p) {
  return *reinterpret_cast<const bf16x4*>(p);
}
__device__ __forceinline__ void st8(bf16_t* p, bf16x8 v) {
  *reinterpret_cast<bf16x8*>(p) = v;
}
__device__ __forceinline__ void store_out(bf16_t* p, float v) { *p = __float2bfloat16(v); }
__device__ __forceinline__ void store_out(float* p, float v)  { *p = v; }

// async global->LDS, 16B per lane. LDS dest is wave-uniform base + lane*16.
__device__ __forceinline__ void async16(const bf16_t* g, bf16_t* l) {
  __builtin_amdgcn_global_load_lds(
      (const __attribute__((address_space(1))) void*)g,
      (__attribute__((address_space(3))) void*)l, 16, 0, 0);
}

// ---------------------------------------------------------------------------
// f32 -> bf16 conversion; folds softmax scale (1/8 * log2e) into Wq.
// ---------------------------------------------------------------------------
__global__ __launch_bounds__(256) void cvt_kernel(
    const float* __restrict__ x,  const float* __restrict__ Wq,
    const float* __restrict__ Wk, const float* __restrict__ Wv,
    const float* __restrict__ Wo,
    bf16_t* __restrict__ xb,  bf16_t* __restrict__ Wqb,
    bf16_t* __restrict__ Wkb, bf16_t* __restrict__ Wvb,
    bf16_t* __restrict__ Wob) {
  const int bid = blockIdx.x;
  const float* src; bf16_t* dst; size_t base;
  float scl = 1.0f;
  if (bid < 2048)      { src = x;  dst = xb;  base = (size_t)bid * 2048; }
  else if (bid < 2560) { src = Wq; dst = Wqb; base = (size_t)(bid - 2048) * 2048;
                         scl = 0.180336878f; }  // 0.125 * log2(e)
  else if (bid < 3072) { src = Wk; dst = Wkb; base = (size_t)(bid - 2560) * 2048; }
  else if (bid < 3584) { src = Wv; dst = Wvb; base = (size_t)(bid - 3072) * 2048; }
  else                 { src = Wo; dst = Wob; base = (size_t)(bid - 3584) * 2048; }
  const size_t i0 = base + (size_t)threadIdx.x * 8;
  const float4 f0 = *reinterpret_cast<const float4*>(src + i0);
  const float4 f1 = *reinterpret_cast<const float4*>(src + i0 + 4);
  bf16x8 v;
  v[0] = (__bf16)(f0.x * scl); v[1] = (__bf16)(f0.y * scl);
  v[2] = (__bf16)(f0.z * scl); v[3] = (__bf16)(f0.w * scl);
  v[4] = (__bf16)(f1.x * scl); v[5] = (__bf16)(f1.y * scl);
  v[6] = (__bf16)(f1.z * scl); v[7] = (__bf16)(f1.w * scl);
  st8(dst + i0, v);
}

// ---------------------------------------------------------------------------
// GEMM tile: C[128x128] = A[128xK] * B[128xK]^T, K=1024, BK=64.
// global_load_lds width-16 staging with XOR-chunk swizzle.
// ---------------------------------------------------------------------------
#define GK 1024

template <typename OutT, bool BIAS>
__device__ __forceinline__ void gemm_tile(
    const bf16_t* __restrict__ A, const bf16_t* __restrict__ B,
    OutT* __restrict__ C, const float* __restrict__ bias,
    int bm, int bn, int ldc, bf16_t* As, bf16_t* Bs) {
  const int tid  = threadIdx.x;
  const int lane = tid & 63;
  const int wave = tid >> 6;
  const int wm   = (wave & 1) << 6;
  const int wn   = (wave >> 1) << 6;
  const int lr   = lane & 15;
  const int lq   = lane >> 4;

  const int srow = tid >> 3;                        // 0..31
  const int sx   = ((tid & 7) ^ (srow & 7)) << 3;   // swizzled source offset

  const bf16_t* Ag = A + (size_t)(bm + srow) * GK + sx;
  const bf16_t* Bg = B + (size_t)(bn + srow) * GK + sx;
  bf16_t* Asw = As + wave * 512;
  bf16_t* Bsw = Bs + wave * 512;

  f32x4 acc[4][4];
#pragma unroll
  for (int i = 0; i < 4; ++i)
#pragma unroll
    for (int j = 0; j < 4; ++j) acc[i][j] = (f32x4){0.f, 0.f, 0.f, 0.f};

  for (int k0 = 0; k0 < GK; k0 += 64) {
    __syncthreads();
#pragma unroll
    for (int g = 0; g < 4; ++g) {
      async16(Ag + k0 + (size_t)(g * 32) * GK, Asw + g * 2048);
      async16(Bg + k0 + (size_t)(g * 32) * GK, Bsw + g * 2048);
    }
    __syncthreads();
#pragma unroll
    for (int ks = 0; ks < 2; ++ks) {
      bf16x8 af[4], bf[4];
      const int chs = ((ks * 4 + lq) ^ (lr & 7)) << 3;
#pragma unroll
      for (int i = 0; i < 4; ++i) {
        af[i] = ldg8(&As[(wm + i * 16 + lr) * 64 + chs]);
        bf[i] = ldg8(&Bs[(wn + i * 16 + lr) * 64 + chs]);
      }
#pragma unroll
      for (int mi = 0; mi < 4; ++mi)
#pragma unroll
        for (int ni = 0; ni < 4; ++ni)
          acc[mi][ni] = MFMA(af[mi], bf[ni], acc[mi][ni]);
    }
  }

  // C/D layout: col = lane&15, row = (lane>>4)*4 + r  (m89-verified)
#pragma unroll
  for (int ni = 0; ni < 4; ++ni) {
    const int col = bn + wn + ni * 16 + lr;
    float bv = 0.f;
    if (BIAS) bv = bias[col];
#pragma unroll
    for (int mi = 0; mi < 4; ++mi) {
#pragma unroll
      for (int r = 0; r < 4; ++r) {
        const int row = bm + wm + mi * 16 + lq * 4 + r;
        store_out(&C[(size_t)row * ldc + col], acc[mi][ni][r] + bv);
      }
    }
  }
}

// XCD-aware remap: same-x-tile blocks share bid%8 -> same XCD L2.
// z=0: Q = x Wq^T;  z=1: K = x Wk^T;  z=2: Vt = Wv x^T [1024x4096]
__global__ __launch_bounds__(256) void qkv_kernel(
    const bf16_t* __restrict__ x, const bf16_t* __restrict__ Wq,
    const bf16_t* __restrict__ Wk, const bf16_t* __restrict__ Wv,
    bf16_t* __restrict__ Q, bf16_t* __restrict__ Kp, bf16_t* __restrict__ Vt) {
  __shared__ alignas(16) bf16_t As[128 * 64];
  __shared__ alignas(16) bf16_t Bs[128 * 64];
  const int bid = blockIdx.x;
  const int z   = blockIdx.y;
  const int mt  = (bid & 31) * 128;   // x token-tile; XCD = bid%8 = mt-tile%8
  const int nt  = (bid >> 5) * 128;
  if (z == 0) {
    gemm_tile<bf16_t, false>(x, Wq, Q, nullptr, mt, nt, 1024, As, Bs);
  } else if (z == 1) {
    gemm_tile<bf16_t, false>(x, Wk, Kp, nullptr, mt, nt, 1024, As, Bs);
  } else {
    gemm_tile<bf16_t, false>(Wv, x, Vt, nullptr, nt, mt, 4096, As, Bs);
  }
}

__global__ __launch_bounds__(256) void out_proj_kernel(
    const bf16_t* __restrict__ Ao, const bf16_t* __restrict__ Wo,
    const float* __restrict__ bias, float* __restrict__ out) {
  __shared__ alignas(16) bf16_t As[128 * 64];
  __shared__ alignas(16) bf16_t Bs[128 * 64];
  const int bid = blockIdx.x;
  gemm_tile<float, true>(Ao, Wo, out, bias, (bid & 31) * 128, (bid >> 5) * 128, 1024, As, Bs);
}

// ---------------------------------------------------------------------------
// Attention: LDS-staged K/V + register-resident P (S^T formulation).
// grid (32 bh, 32 qt) -> all q-tiles of one (b,h) share an XCD (K/V L2-local).
// Per wave: 16 q-rows (q = lane&15), full 64-kv tile. S^T = K(A,LDS) x Q(B,regs)
// via 16x16x32; S^T C-layout (k=kv=quad*4+r, n=q) IS the 16x16x16 B-layout ->
// P = exp2(S^T) feeds O^T += Vt(A,LDS) x P straight from registers. No P LDS
// round-trip, no ones-MFMA (l is a per-lane scalar + 2 end shuffles), no
// cross-wave reduction. Epilogue: wave-private LDS bounce to transpose O^T.
// ---------------------------------------------------------------------------
#define VPAD 68

__global__ __launch_bounds__(256) void attn_kernel(
    const bf16_t* __restrict__ Q, const bf16_t* __restrict__ Kp,
    const bf16_t* __restrict__ Vt, bf16_t* __restrict__ Ao) {
  __shared__ alignas(16) bf16_t Ks[64 * 64];     // [kv][hd], XOR-swizzled chunks
  __shared__ alignas(16) bf16_t Vs[64 * VPAD];   // [hd][kv], padded
  __shared__ float Osc[4][64 * 17];              // epilogue transpose scratch

  const int tid  = threadIdx.x;
  const int lane = tid & 63;
  const int wave = tid >> 6;
  const int lr   = lane & 15;
  const int lq   = lane >> 4;
  const int bh   = blockIdx.x;
  const int qt   = blockIdx.y;
  const int b    = bh >> 4;
  const int h    = bh & 15;
  const size_t tok0 = (size_t)b * 2048;
  const int col0 = h * 64;

  // Q B-frags (n = q = lane&15, k = hd = c*32 + lq*8 + i), held in regs
  const size_t qrow = tok0 + qt * 64 + wave * 16 + lr;
  bf16x8 qf[2];
  qf[0] = ldg8(&Q[qrow * 1024 + col0 + lq * 8]);
  qf[1] = ldg8(&Q[qrow * 1024 + col0 + 32 + lq * 8]);

  f32x4 o[4];  // O^T accum: [ht] tiles, D[m=hd=ht*16+lq*4+r][n=q=lr]
#pragma unroll
  for (int i = 0; i < 4; ++i) o[i] = (f32x4){0.f, 0.f, 0.f, 0.f};
  float lsum = 0.f;

  // staging: rows srow, srow+32; K via async16 (XOR swizzle), V manual (pad)
  const int srow = tid >> 3;                       // 0..31
  const int sxk  = ((tid & 7) ^ (srow & 7)) << 3;  // K swizzled source chunk
  const int sxv  = (tid & 7) << 3;
  bf16_t* Ksw = Ks + wave * 512;

  // frag-read LDS offsets (elems)
  const int koff0 = lr * 64 + ((lq ^ (lr & 7)) << 3);
  const int koff1 = lr * 64 + (((lq + 4) ^ (lr & 7)) << 3);
  const int voff  = lr * VPAD + lq * 4;

  for (int kv0 = 0; kv0 < 2048; kv0 += 64) {
    const bf16_t* Kg = Kp + (tok0 + kv0) * 1024 + col0;
    const bf16_t* Vg = Vt + (size_t)col0 * 4096 + tok0 + kv0;
    const bf16x8 v0 = ldg8(Vg + (size_t)srow * 4096 + sxv);
    const bf16x8 v1 = ldg8(Vg + (size_t)(srow + 32) * 4096 + sxv);
    __syncthreads();
    async16(Kg + (size_t)srow * 1024 + sxk, Ksw);
    async16(Kg + (size_t)(srow + 32) * 1024 + sxk, Ksw + 2048);
    st8(&Vs[srow * VPAD + sxv], v0);
    st8(&Vs[(srow + 32) * VPAD + sxv], v1);
    __syncthreads();

#pragma unroll
    for (int c = 0; c < 4; ++c) {
      const bf16x8 kf0 = ldg8(&Ks[c * 1024 + koff0]);
      const bf16x8 kf1 = ldg8(&Ks[c * 1024 + koff1]);
      f32x4 sT = {0.f, 0.f, 0.f, 0.f};
      sT = MFMA(kf0, qf[0], sT);
      sT = MFMA(kf1, qf[1], sT);
      const float p0 = exp2f(sT.x);
      const float p1 = exp2f(sT.y);
      const float p2 = exp2f(sT.z);
      const float p3 = exp2f(sT.w);
      bf16x4 pb;
      pb[0] = (__bf16)p0; pb[1] = (__bf16)p1;
      pb[2] = (__bf16)p2; pb[3] = (__bf16)p3;
      lsum += (p0 + p1) + (p2 + p3);
#pragma unroll
      for (int ht = 0; ht < 4; ++ht) {
        const bf16x4 vf = ldg4(&Vs[ht * 16 * VPAD + voff + c * 16]);
        o[ht] = mfma16(vf, pb, o[ht]);
      }
    }
  }

  // l: per-lane partial over kv ≡ lq quadrant; reduce across lq (xor 16, 32)
  lsum += __shfl_xor(lsum, 16);
  lsum += __shfl_xor(lsum, 32);
  const float invl = 1.f / lsum;

  // epilogue: wave-private transpose bounce (in-wave LDS ordering, no barrier)
  float* Ow = &Osc[wave][0];
#pragma unroll
  for (int ht = 0; ht < 4; ++ht)
#pragma unroll
    for (int r = 0; r < 4; ++r)
      Ow[(ht * 16 + lq * 4 + r) * 17 + lr] = o[ht][r] * invl;

  const int qq = lane >> 2;          // 0..15
  const int hc = (lane & 3) * 16;    // hd segment
  bf16x8 w0, w1;
#pragma unroll
  for (int i = 0; i < 8; ++i) {
    w0[i] = (__bf16)Ow[(hc + i) * 17 + qq];
    w1[i] = (__bf16)Ow[(hc + 8 + i) * 17 + qq];
  }
  bf16_t* dst = Ao + (tok0 + qt * 64 + wave * 16 + qq) * 1024 + col0 + hc;
  st8(dst, w0);
  st8(dst + 8, w1);
}

extern "C" void kernel_launch(void* const* d_in, const int* in_sizes, int n_in,
                              void* d_out, int out_size, void* d_ws, size_t ws_size,
                              hipStream_t stream) {
  const float* x  = (const float*)d_in[0];
  const float* Wq = (const float*)d_in[1];
  const float* Wk = (const float*)d_in[2];
  const float* Wv = (const float*)d_in[3];
  const float* Wo = (const float*)d_in[4];
  const float* bo = (const float*)d_in[5];
  float* out = (float*)d_out;

  const size_t NTOK = 4096, DMODEL = 1024, WSZ = DMODEL * DMODEL;
  bf16_t* xb  = (bf16_t*)d_ws;
  bf16_t* Wqb = xb + NTOK * DMODEL;
  bf16_t* Wkb = Wqb + WSZ;
  bf16_t* Wvb = Wkb + WSZ;
  bf16_t* Wob = Wvb + WSZ;
  bf16_t* Q   = Wob + WSZ;
  bf16_t* Kp  = Q  + NTOK * DMODEL;
  bf16_t* Vt  = Kp + NTOK * DMODEL;            // [1024][4096] = V^T
  bf16_t* Ao  = Vt + NTOK * DMODEL;

  cvt_kernel<<<dim3(4096), 256, 0, stream>>>(x, Wq, Wk, Wv, Wo, xb, Wqb, Wkb, Wvb, Wob);
  qkv_kernel<<<dim3(256, 3), 256, 0, stream>>>(xb, Wqb, Wkb, Wvb, Q, Kp, Vt);
  attn_kernel<<<dim3(32, 32), 256, 0, stream>>>(Q, Kp, Vt, Ao);
  out_proj_kernel<<<dim3(256, 1), 256, 0, stream>>>(Ao, Wob, bo, out);
}

// Round 6
// 209.188 us; speedup vs baseline: 1.4620x; 1.0415x over previous
//
#include <hip/hip_runtime.h>
#include <hip/hip_bf16.h>

typedef __hip_bfloat16 bf16_t;
typedef __bf16 bf16x8 __attribute__((ext_vector_type(8)));      // 16x16x32 A/B frag
typedef __bf16 bf16x4 __attribute__((ext_vector_type(4)));      // 16x16x16 A/B frag
typedef short  s16x4  __attribute__((ext_vector_type(4)));
typedef float  f32x4  __attribute__((ext_vector_type(4)));      // C/D frag

#define MFMA(a, b, c) __builtin_amdgcn_mfma_f32_16x16x32_bf16((a), (b), (c), 0, 0, 0)

__device__ __forceinline__ f32x4 mfma16(bf16x4 a, bf16x4 b, f32x4 c) {
#if __has_builtin(__builtin_amdgcn_mfma_f32_16x16x16_bf16)
  return __builtin_amdgcn_mfma_f32_16x16x16_bf16(a, b, c, 0, 0, 0);
#else
  return __builtin_amdgcn_mfma_f32_16x16x16bf16_1k(
      __builtin_bit_cast(s16x4, a), __builtin_bit_cast(s16x4, b), c, 0, 0, 0);
#endif
}

__device__ __forceinline__ bf16x8 ldg8(const bf16_t* p) {
  return *reinterpret_cast<const bf16x8*>(p);
}
__device__ __forceinline__ bf16x4 ldg4(const bf16_t* p) {
  return *reinterpret_cast<const bf16x4*>(p);
}
__device__ __forceinline__ void st8(bf16_t* p, bf16x8 v) {
  *reinterpret_cast<bf16x8*>(p) = v;
}
__device__ __forceinline__ void store_out(bf16_t* p, float v) { *p = __float2bfloat16(v); }
__device__ __forceinline__ void store_out(float* p, float v)  { *p = v; }

// async global->LDS, 16B per lane. LDS dest is wave-uniform base + lane*16.
__device__ __forceinline__ void async16(const bf16_t* g, bf16_t* l) {
  __builtin_amdgcn_global_load_lds(
      (const __attribute__((address_space(1))) void*)g,
      (__attribute__((address_space(3))) void*)l, 16, 0, 0);
}

// ---------------------------------------------------------------------------
// f32 -> bf16 conversion; folds softmax scale (1/8 * log2e) into Wq.
// ---------------------------------------------------------------------------
__global__ __launch_bounds__(256) void cvt_kernel(
    const float* __restrict__ x,  const float* __restrict__ Wq,
    const float* __restrict__ Wk, const float* __restrict__ Wv,
    const float* __restrict__ Wo,
    bf16_t* __restrict__ xb,  bf16_t* __restrict__ Wqb,
    bf16_t* __restrict__ Wkb, bf16_t* __restrict__ Wvb,
    bf16_t* __restrict__ Wob) {
  const int bid = blockIdx.x;
  const float* src; bf16_t* dst; size_t base;
  float scl = 1.0f;
  if (bid < 2048)      { src = x;  dst = xb;  base = (size_t)bid * 2048; }
  else if (bid < 2560) { src = Wq; dst = Wqb; base = (size_t)(bid - 2048) * 2048;
                         scl = 0.180336878f; }  // 0.125 * log2(e)
  else if (bid < 3072) { src = Wk; dst = Wkb; base = (size_t)(bid - 2560) * 2048; }
  else if (bid < 3584) { src = Wv; dst = Wvb; base = (size_t)(bid - 3072) * 2048; }
  else                 { src = Wo; dst = Wob; base = (size_t)(bid - 3584) * 2048; }
  const size_t i0 = base + (size_t)threadIdx.x * 8;
  const float4 f0 = *reinterpret_cast<const float4*>(src + i0);
  const float4 f1 = *reinterpret_cast<const float4*>(src + i0 + 4);
  bf16x8 v;
  v[0] = (__bf16)(f0.x * scl); v[1] = (__bf16)(f0.y * scl);
  v[2] = (__bf16)(f0.z * scl); v[3] = (__bf16)(f0.w * scl);
  v[4] = (__bf16)(f1.x * scl); v[5] = (__bf16)(f1.y * scl);
  v[6] = (__bf16)(f1.z * scl); v[7] = (__bf16)(f1.w * scl);
  st8(dst + i0, v);
}

// ---------------------------------------------------------------------------
// GEMM tile: C[128x128] = A[128xK] * B[128xK]^T, K=1024, BK=64.
// global_load_lds width-16 staging with XOR-chunk swizzle.
// ---------------------------------------------------------------------------
#define GK 1024

template <typename OutT, bool BIAS>
__device__ __forceinline__ void gemm_tile(
    const bf16_t* __restrict__ A, const bf16_t* __restrict__ B,
    OutT* __restrict__ C, const float* __restrict__ bias,
    int bm, int bn, int ldc, bf16_t* As, bf16_t* Bs) {
  const int tid  = threadIdx.x;
  const int lane = tid & 63;
  const int wave = tid >> 6;
  const int wm   = (wave & 1) << 6;
  const int wn   = (wave >> 1) << 6;
  const int lr   = lane & 15;
  const int lq   = lane >> 4;

  const int srow = tid >> 3;                        // 0..31
  const int sx   = ((tid & 7) ^ (srow & 7)) << 3;   // swizzled source offset

  const bf16_t* Ag = A + (size_t)(bm + srow) * GK + sx;
  const bf16_t* Bg = B + (size_t)(bn + srow) * GK + sx;
  bf16_t* Asw = As + wave * 512;
  bf16_t* Bsw = Bs + wave * 512;

  f32x4 acc[4][4];
#pragma unroll
  for (int i = 0; i < 4; ++i)
#pragma unroll
    for (int j = 0; j < 4; ++j) acc[i][j] = (f32x4){0.f, 0.f, 0.f, 0.f};

  for (int k0 = 0; k0 < GK; k0 += 64) {
    __syncthreads();
#pragma unroll
    for (int g = 0; g < 4; ++g) {
      async16(Ag + k0 + (size_t)(g * 32) * GK, Asw + g * 2048);
      async16(Bg + k0 + (size_t)(g * 32) * GK, Bsw + g * 2048);
    }
    __syncthreads();
#pragma unroll
    for (int ks = 0; ks < 2; ++ks) {
      bf16x8 af[4], bf[4];
      const int chs = ((ks * 4 + lq) ^ (lr & 7)) << 3;
#pragma unroll
      for (int i = 0; i < 4; ++i) {
        af[i] = ldg8(&As[(wm + i * 16 + lr) * 64 + chs]);
        bf[i] = ldg8(&Bs[(wn + i * 16 + lr) * 64 + chs]);
      }
#pragma unroll
      for (int mi = 0; mi < 4; ++mi)
#pragma unroll
        for (int ni = 0; ni < 4; ++ni)
          acc[mi][ni] = MFMA(af[mi], bf[ni], acc[mi][ni]);
    }
  }

  // C/D layout: col = lane&15, row = (lane>>4)*4 + r  (m89-verified)
#pragma unroll
  for (int ni = 0; ni < 4; ++ni) {
    const int col = bn + wn + ni * 16 + lr;
    float bv = 0.f;
    if (BIAS) bv = bias[col];
#pragma unroll
    for (int mi = 0; mi < 4; ++mi) {
#pragma unroll
      for (int r = 0; r < 4; ++r) {
        const int row = bm + wm + mi * 16 + lq * 4 + r;
        store_out(&C[(size_t)row * ldc + col], acc[mi][ni][r] + bv);
      }
    }
  }
}

// XCD-aware remap: same-x-tile blocks share bid%8 -> same XCD L2.
// z=0: Q = x Wq^T;  z=1: K = x Wk^T;  z=2: Vt = Wv x^T [1024x4096]
__global__ __launch_bounds__(256) void qkv_kernel(
    const bf16_t* __restrict__ x, const bf16_t* __restrict__ Wq,
    const bf16_t* __restrict__ Wk, const bf16_t* __restrict__ Wv,
    bf16_t* __restrict__ Q, bf16_t* __restrict__ Kp, bf16_t* __restrict__ Vt) {
  __shared__ alignas(16) bf16_t As[128 * 64];
  __shared__ alignas(16) bf16_t Bs[128 * 64];
  const int bid = blockIdx.x;
  const int z   = blockIdx.y;
  const int mt  = (bid & 31) * 128;   // x token-tile; XCD = bid%8 = mt-tile%8
  const int nt  = (bid >> 5) * 128;
  if (z == 0) {
    gemm_tile<bf16_t, false>(x, Wq, Q, nullptr, mt, nt, 1024, As, Bs);
  } else if (z == 1) {
    gemm_tile<bf16_t, false>(x, Wk, Kp, nullptr, mt, nt, 1024, As, Bs);
  } else {
    gemm_tile<bf16_t, false>(Wv, x, Vt, nullptr, nt, mt, 4096, As, Bs);
  }
}

__global__ __launch_bounds__(256) void out_proj_kernel(
    const bf16_t* __restrict__ Ao, const bf16_t* __restrict__ Wo,
    const float* __restrict__ bias, float* __restrict__ out) {
  __shared__ alignas(16) bf16_t As[128 * 64];
  __shared__ alignas(16) bf16_t Bs[128 * 64];
  const int bid = blockIdx.x;
  gemm_tile<float, true>(Ao, Wo, out, bias, (bid & 31) * 128, (bid >> 5) * 128, 1024, As, Bs);
}

// ---------------------------------------------------------------------------
// Attention: LDS-staged K/V + register-resident P (S^T), 32 q-rows per wave.
// grid (32 bh, 16 qt): block = 128 q-rows, 4 waves x 2 q-subtiles ("nt").
// K-frags and V-frags are read from LDS ONCE and feed BOTH nt streams ->
// per-q LDS traffic halves vs 16-q waves (R5's bottleneck).
// S^T = K(A,LDS) x Q(B,regs) via 16x16x32; its C-layout (k=kv=quad*4+r, n=q)
// IS the 16x16x16 B-layout, so P = exp2(S^T) feeds O^T += Vt(A,LDS) x P from
// registers. l = per-lane scalar + 2 end shuffles. Epilogue transposes O^T
// via LDS scratch overlaid on Ks/Vs (barrier after the kv loop).
// ---------------------------------------------------------------------------
#define VPAD 68

__global__ __launch_bounds__(256) void attn_kernel(
    const bf16_t* __restrict__ Q, const bf16_t* __restrict__ Kp,
    const bf16_t* __restrict__ Vt, bf16_t* __restrict__ Ao) {
  __shared__ alignas(16) char smem_raw[4 * 64 * 17 * 4];  // 17408 B
  bf16_t* Ks = (bf16_t*)smem_raw;                  // [64 kv][64 hd], swizzled
  bf16_t* Vs = (bf16_t*)(smem_raw + 8192);         // [64 hd][VPAD kv]
  float*  Osc = (float*)smem_raw;                  // epilogue scratch

  const int tid  = threadIdx.x;
  const int lane = tid & 63;
  const int wave = tid >> 6;
  const int lr   = lane & 15;
  const int lq   = lane >> 4;
  const int bh   = blockIdx.x;
  const int qt   = blockIdx.y;
  const int b    = bh >> 4;
  const int h    = bh & 15;
  const size_t tok0 = (size_t)b * 2048;
  const int col0 = h * 64;
  const int qblk = qt * 128 + wave * 32;           // wave's 32 q-rows

  // Q B-frags (n = q = lane&15, k = hd = c*32 + lq*8 + i), held in regs
  bf16x8 qf[2][2];
#pragma unroll
  for (int nt = 0; nt < 2; ++nt) {
    const size_t qrow = tok0 + qblk + nt * 16 + lr;
#pragma unroll
    for (int c = 0; c < 2; ++c)
      qf[nt][c] = ldg8(&Q[qrow * 1024 + col0 + c * 32 + lq * 8]);
  }

  f32x4 o[2][4];  // O^T accum per nt: D[m=hd=ht*16+lq*4+r][n=q=lr]
#pragma unroll
  for (int nt = 0; nt < 2; ++nt)
#pragma unroll
    for (int i = 0; i < 4; ++i) o[nt][i] = (f32x4){0.f, 0.f, 0.f, 0.f};
  float lsum[2] = {0.f, 0.f};

  // staging: rows srow, srow+32; K via async16 (XOR swizzle), V manual (pad)
  const int srow = tid >> 3;                       // 0..31
  const int sxk  = ((tid & 7) ^ (srow & 7)) << 3;  // K swizzled source chunk
  const int sxv  = (tid & 7) << 3;
  bf16_t* Ksw = Ks + wave * 512;

  // frag-read LDS offsets (elems)
  const int koff0 = lr * 64 + ((lq ^ (lr & 7)) << 3);
  const int koff1 = lr * 64 + (((lq + 4) ^ (lr & 7)) << 3);
  const int voff  = lr * VPAD + lq * 4;

  for (int kv0 = 0; kv0 < 2048; kv0 += 64) {
    const bf16_t* Kg = Kp + (tok0 + kv0) * 1024 + col0;
    const bf16_t* Vg = Vt + (size_t)col0 * 4096 + tok0 + kv0;
    const bf16x8 v0 = ldg8(Vg + (size_t)srow * 4096 + sxv);
    const bf16x8 v1 = ldg8(Vg + (size_t)(srow + 32) * 4096 + sxv);
    __syncthreads();
    async16(Kg + (size_t)srow * 1024 + sxk, Ksw);
    async16(Kg + (size_t)(srow + 32) * 1024 + sxk, Ksw + 2048);
    st8(&Vs[srow * VPAD + sxv], v0);
    st8(&Vs[(srow + 32) * VPAD + sxv], v1);
    __syncthreads();

#pragma unroll
    for (int c = 0; c < 4; ++c) {
      const bf16x8 kf0 = ldg8(&Ks[c * 1024 + koff0]);
      const bf16x8 kf1 = ldg8(&Ks[c * 1024 + koff1]);
      bf16x4 pb[2];
#pragma unroll
      for (int nt = 0; nt < 2; ++nt) {
        f32x4 sT = {0.f, 0.f, 0.f, 0.f};
        sT = MFMA(kf0, qf[nt][0], sT);
        sT = MFMA(kf1, qf[nt][1], sT);
        const float p0 = exp2f(sT.x);
        const float p1 = exp2f(sT.y);
        const float p2 = exp2f(sT.z);
        const float p3 = exp2f(sT.w);
        pb[nt][0] = (__bf16)p0; pb[nt][1] = (__bf16)p1;
        pb[nt][2] = (__bf16)p2; pb[nt][3] = (__bf16)p3;
        lsum[nt] += (p0 + p1) + (p2 + p3);
      }
#pragma unroll
      for (int ht = 0; ht < 4; ++ht) {
        const bf16x4 vf = ldg4(&Vs[ht * 16 * VPAD + voff + c * 16]);
        o[0][ht] = mfma16(vf, pb[0], o[0][ht]);
        o[1][ht] = mfma16(vf, pb[1], o[1][ht]);
      }
    }
  }

  // make sure all waves are done with Ks/Vs before overlaying scratch
  __syncthreads();

  float* Ow = &Osc[wave * 64 * 17];
#pragma unroll
  for (int nt = 0; nt < 2; ++nt) {
    // l: per-lane partial over kv ≡ lq quadrant; reduce across lq
    float ls = lsum[nt];
    ls += __shfl_xor(ls, 16);
    ls += __shfl_xor(ls, 32);
    const float invl = 1.f / ls;

    // wave-private transpose bounce (in-wave DS ordering, no barrier)
#pragma unroll
    for (int ht = 0; ht < 4; ++ht)
#pragma unroll
      for (int r = 0; r < 4; ++r)
        Ow[(ht * 16 + lq * 4 + r) * 17 + lr] = o[nt][ht][r] * invl;

    const int qq = lane >> 2;          // 0..15
    const int hc = (lane & 3) * 16;    // hd segment
    bf16x8 w0, w1;
#pragma unroll
    for (int i = 0; i < 8; ++i) {
      w0[i] = (__bf16)Ow[(hc + i) * 17 + qq];
      w1[i] = (__bf16)Ow[(hc + 8 + i) * 17 + qq];
    }
    bf16_t* dst = Ao + (tok0 + qblk + nt * 16 + qq) * 1024 + col0 + hc;
    st8(dst, w0);
    st8(dst + 8, w1);
  }
}

extern "C" void kernel_launch(void* const* d_in, const int* in_sizes, int n_in,
                              void* d_out, int out_size, void* d_ws, size_t ws_size,
                              hipStream_t stream) {
  const float* x  = (const float*)d_in[0];
  const float* Wq = (const float*)d_in[1];
  const float* Wk = (const float*)d_in[2];
  const float* Wv = (const float*)d_in[3];
  const float* Wo = (const float*)d_in[4];
  const float* bo = (const float*)d_in[5];
  float* out = (float*)d_out;

  const size_t NTOK = 4096, DMODEL = 1024, WSZ = DMODEL * DMODEL;
  bf16_t* xb  = (bf16_t*)d_ws;
  bf16_t* Wqb = xb + NTOK * DMODEL;
  bf16_t* Wkb = Wqb + WSZ;
  bf16_t* Wvb = Wkb + WSZ;
  bf16_t* Wob = Wvb + WSZ;
  bf16_t* Q   = Wob + WSZ;
  bf16_t* Kp  = Q  + NTOK * DMODEL;
  bf16_t* Vt  = Kp + NTOK * DMODEL;            // [1024][4096] = V^T
  bf16_t* Ao  = Vt + NTOK * DMODEL;

  cvt_kernel<<<dim3(4096), 256, 0, stream>>>(x, Wq, Wk, Wv, Wo, xb, Wqb, Wkb, Wvb, Wob);
  qkv_kernel<<<dim3(256, 3), 256, 0, stream>>>(xb, Wqb, Wkb, Wvb, Q, Kp, Vt);
  attn_kernel<<<dim3(32, 16), 256, 0, stream>>>(Q, Kp, Vt, Ao);
  out_proj_kernel<<<dim3(256, 1), 256, 0, stream>>>(Ao, Wob, bo, out);
}